// Round 2
// baseline (463.810 us; speedup 1.0000x reference)
//
#include <hip/hip_runtime.h>
#include <stdint.h>

#define N_NODES 50000
#define N_EDGES 800000
#define HF 128          // HEADS * OUT_F
#define NEG_SLOPE 0.2f
#define EPS_F 1e-8f

// ---------- helpers ----------
__device__ __forceinline__ float bf2f(unsigned short u) {
    union { unsigned int i; float f; } v; v.i = ((unsigned int)u) << 16; return v.f;
}
__device__ __forceinline__ unsigned short f2bf(float f) {
    union { unsigned int i; float f; } v; v.f = f;
    unsigned int b = v.i;
    unsigned int r = (b + 0x7FFFu + ((b >> 16) & 1u)) >> 16;   // round-to-nearest-even
    return (unsigned short)r;
}

// ---------- K0: dtype sniff ----------
// flags[0] = 1 if float inputs are bf16 on device, 0 if f32
// flags[1] = 1 if edge_index is int64 on device, 0 if int32
__global__ void k_sniff(const void* x, const void* eidx, int* flags) {
    int l = threadIdx.x;  // 64 threads
    const unsigned short* xu = (const unsigned short*)x;
    float f = bf2f(xu[2 * l]);
    float af = fabsf(f);
    // For a true f32 buffer, xu[2l] is mantissa junk -> extreme exponent when read as bf16.
    bool extreme = !(af <= 1e6f) || (f != 0.0f && af < 1e-7f);
    unsigned long long mask = __ballot(extreme);
    const unsigned int* eu = (const unsigned int*)eidx;
    unsigned int w = eu[2 * l + 1];
    unsigned long long mask2 = __ballot(w != 0u);
    if (l == 0) {
        flags[0] = (__popcll(mask) >= 8) ? 0 : 1;
        flags[1] = (__popcll(mask2) >= 4) ? 0 : 1;
    }
}

// ---------- K1: normalize W, a_src, a_dst, edge_index into ws ----------
__global__ void k_convert(const void* W, const void* a_src, const void* a_dst, const void* eidx,
                          float* Wf, float* af, int* srcI, int* dstI, const int* flags) {
    int i = blockIdx.x * blockDim.x + threadIdx.x;
    int isB = flags[0], is64 = flags[1];
    if (i < 16384) Wf[i] = isB ? bf2f(((const unsigned short*)W)[i]) : ((const float*)W)[i];
    if (i < 128) {
        af[i]       = isB ? bf2f(((const unsigned short*)a_src)[i]) : ((const float*)a_src)[i];
        af[128 + i] = isB ? bf2f(((const unsigned short*)a_dst)[i]) : ((const float*)a_dst)[i];
    }
    if (i < N_EDGES) {
        int s, d;
        if (is64) {
            s = (int)((const long long*)eidx)[i];
            d = (int)((const long long*)eidx)[N_EDGES + i];
        } else {
            s = ((const int*)eidx)[i];
            d = ((const int*)eidx)[N_EDGES + i];
        }
        srcI[i] = s; dstI[i] = d;
    }
}

// ---------- K2: h = x @ W^T  (+ fused per-node scores s_src, s_dst) ----------
// Block 256 threads, 32 nodes/block (4 passes x 8 nodes). W staged bf16 in LDS (stride 132).
__global__ __launch_bounds__(256) void k_gemm(const void* x, const float* Wf, const float* af,
                                              float* h, float* s_src, float* s_dst, const int* flags) {
    __shared__ unsigned short WtU[128 * 132];  // [k][o], padded
    __shared__ float xs[8 * 128];
    __shared__ float aS[128], aD[128];
    int tid = threadIdx.x;
    for (int idx = tid; idx < 16384; idx += 256) {
        int o = idx >> 7, k = idx & 127;
        WtU[k * 132 + o] = f2bf(Wf[idx]);
    }
    if (tid < 128) { aS[tid] = af[tid]; aD[tid] = af[128 + tid]; }
    int isB = flags[0];
    int ln = tid >> 5, og = tid & 31, hd = og >> 3, j = og & 7;
    const unsigned short* xu = (const unsigned short*)x;
    const float* xf = (const float*)x;
    for (int pass = 0; pass < 4; ++pass) {
        int nodeBase = blockIdx.x * 32 + pass * 8;
        __syncthreads();
        for (int idx = tid; idx < 1024; idx += 256) {
            int nn = nodeBase + (idx >> 7);
            int k = idx & 127;
            float v = 0.0f;
            if (nn < N_NODES) {
                size_t gi = (size_t)nn * 128 + k;
                v = isB ? bf2f(xu[gi]) : xf[gi];
            }
            xs[idx] = v;
        }
        __syncthreads();
        int n = nodeBase + ln;
        float a0 = 0.f, a1 = 0.f, a2 = 0.f, a3 = 0.f;
        #pragma unroll 8
        for (int k = 0; k < 128; ++k) {
            float xv = xs[ln * 128 + k];
            uint2 wv = *(const uint2*)&WtU[k * 132 + og * 4];
            float w0 = bf2f((unsigned short)(wv.x & 0xFFFFu));
            float w1 = bf2f((unsigned short)(wv.x >> 16));
            float w2 = bf2f((unsigned short)(wv.y & 0xFFFFu));
            float w3 = bf2f((unsigned short)(wv.y >> 16));
            a0 += xv * w0; a1 += xv * w1; a2 += xv * w2; a3 += xv * w3;
        }
        if (n < N_NODES) {
            float4 acc = make_float4(a0, a1, a2, a3);
            *(float4*)&h[(size_t)n * HF + og * 4] = acc;
            int fb = og * 4;                   // = hd*32 + j*4
            float4 as4 = *(const float4*)&aS[fb];
            float4 ad4 = *(const float4*)&aD[fb];
            float ps = a0 * as4.x + a1 * as4.y + a2 * as4.z + a3 * as4.w;
            float pd = a0 * ad4.x + a1 * ad4.y + a2 * ad4.z + a3 * ad4.w;
            #pragma unroll
            for (int off = 1; off < 8; off <<= 1) {
                ps += __shfl_xor(ps, off, 64);
                pd += __shfl_xor(pd, off, 64);
            }
            if (j == 0) { s_src[n * 4 + hd] = ps; s_dst[n * 4 + hd] = pd; }
        }
    }
}

// ---------- K3: degree count ----------
__global__ void k_count(const int* dstI, int* counts) {
    int i = blockIdx.x * blockDim.x + threadIdx.x;
    if (i < N_EDGES) atomicAdd(&counts[dstI[i]], 1);
}

// ---------- K4: exclusive scan -> row_start (single block) ----------
__global__ __launch_bounds__(1024) void k_scan(const int* counts, int* row_start) {
    __shared__ int part[1024];
    int t = threadIdx.x;
    const int CH = (N_NODES + 1023) / 1024;
    int base = t * CH;
    int s = 0;
    for (int j = 0; j < CH; ++j) { int idx = base + j; if (idx < N_NODES) s += counts[idx]; }
    part[t] = s;
    __syncthreads();
    for (int off = 1; off < 1024; off <<= 1) {
        int v = (t >= off) ? part[t - off] : 0;
        __syncthreads();
        part[t] += v;
        __syncthreads();
    }
    int run = part[t] - s;   // exclusive base
    for (int j = 0; j < CH; ++j) {
        int idx = base + j;
        if (idx < N_NODES) { row_start[idx] = run; run += counts[idx]; }
    }
    if (t == 1023) row_start[N_NODES] = part[1023];
}

// ---------- K5: scatter edge ids into CSR ----------
__global__ void k_scatter(const int* dstI, const int* row_start, int* cursor, int* csr) {
    int i = blockIdx.x * blockDim.x + threadIdx.x;
    if (i < N_EDGES) {
        int d = dstI[i];
        int p = atomicAdd(&cursor[d], 1);
        csr[row_start[d] + p] = i;
    }
}

// ---------- K6: per-node softmax + aggregation (1 wave = 1 node) ----------
__global__ __launch_bounds__(256) void k_agg(const float* h, const float* s_src, const float* s_dst,
                                             const int* srcI, const int* row_start, const int* csr,
                                             float* out) {
    int wid = threadIdx.x >> 6;
    int l = threadIdx.x & 63;
    int n = blockIdx.x * 4 + wid;
    if (n >= N_NODES) return;
    int rs = row_start[n];
    int deg = row_start[n + 1] - rs;
    if (deg == 0) return;                     // out row stays zero (matches reference)
    float4 sd = *(const float4*)&s_dst[n * 4];

    // pass A: per-head running max
    float m0 = -__builtin_inff(), m1 = m0, m2 = m0, m3 = m0;
    for (int i = l; i < deg; i += 64) {
        int e = csr[rs + i];
        int s = srcI[e];
        float4 ss = *(const float4*)&s_src[s * 4];
        float v0 = ss.x + sd.x; v0 = v0 > 0.f ? v0 : NEG_SLOPE * v0;
        float v1 = ss.y + sd.y; v1 = v1 > 0.f ? v1 : NEG_SLOPE * v1;
        float v2 = ss.z + sd.z; v2 = v2 > 0.f ? v2 : NEG_SLOPE * v2;
        float v3 = ss.w + sd.w; v3 = v3 > 0.f ? v3 : NEG_SLOPE * v3;
        m0 = fmaxf(m0, v0); m1 = fmaxf(m1, v1); m2 = fmaxf(m2, v2); m3 = fmaxf(m3, v3);
    }
    #pragma unroll
    for (int off = 32; off >= 1; off >>= 1) {
        m0 = fmaxf(m0, __shfl_xor(m0, off, 64));
        m1 = fmaxf(m1, __shfl_xor(m1, off, 64));
        m2 = fmaxf(m2, __shfl_xor(m2, off, 64));
        m3 = fmaxf(m3, __shfl_xor(m3, off, 64));
    }

    // pass B: exp-sum
    float z0 = 0.f, z1 = 0.f, z2 = 0.f, z3 = 0.f;
    for (int i = l; i < deg; i += 64) {
        int e = csr[rs + i];
        int s = srcI[e];
        float4 ss = *(const float4*)&s_src[s * 4];
        float v0 = ss.x + sd.x; v0 = v0 > 0.f ? v0 : NEG_SLOPE * v0;
        float v1 = ss.y + sd.y; v1 = v1 > 0.f ? v1 : NEG_SLOPE * v1;
        float v2 = ss.z + sd.z; v2 = v2 > 0.f ? v2 : NEG_SLOPE * v2;
        float v3 = ss.w + sd.w; v3 = v3 > 0.f ? v3 : NEG_SLOPE * v3;
        z0 += __expf(v0 - m0); z1 += __expf(v1 - m1);
        z2 += __expf(v2 - m2); z3 += __expf(v3 - m3);
    }
    #pragma unroll
    for (int off = 32; off >= 1; off >>= 1) {
        z0 += __shfl_xor(z0, off, 64);
        z1 += __shfl_xor(z1, off, 64);
        z2 += __shfl_xor(z2, off, 64);
        z3 += __shfl_xor(z3, off, 64);
    }
    float i0 = 1.f / (z0 + EPS_F), i1 = 1.f / (z1 + EPS_F);
    float i2 = 1.f / (z2 + EPS_F), i3 = 1.f / (z3 + EPS_F);

    // pass C: weighted accumulate. lane l owns outputs o=l (head ha) and o=64+l (head 2+ha)
    int ha = l >> 5;
    float sda = ha ? sd.y : sd.x, sdb = ha ? sd.w : sd.z;
    float ma  = ha ? m1 : m0,     mb  = ha ? m3 : m2;
    float ia  = ha ? i1 : i0,     ib  = ha ? i3 : i2;
    float accA = 0.f, accB = 0.f;
    for (int i = 0; i < deg; ++i) {
        int e = csr[rs + i];
        int s = srcI[e];
        const float* sp = &s_src[s * 4];
        float ssa = sp[ha], ssb = sp[2 + ha];
        float va = ssa + sda; va = va > 0.f ? va : NEG_SLOPE * va;
        float vb = ssb + sdb; vb = vb > 0.f ? vb : NEG_SLOPE * vb;
        float wa = __expf(va - ma) * ia;
        float wb = __expf(vb - mb) * ib;
        const float* hp = &h[(size_t)s * HF];
        accA += wa * hp[l];
        accB += wb * hp[64 + l];
    }
    out[(size_t)n * HF + l] = accA;
    out[(size_t)n * HF + 64 + l] = accB;
}

extern "C" void kernel_launch(void* const* d_in, const int* in_sizes, int n_in,
                              void* d_out, int out_size, void* d_ws, size_t ws_size,
                              hipStream_t stream) {
    const void* x     = d_in[0];
    const void* eidx  = d_in[1];
    const void* W     = d_in[2];
    const void* a_src = d_in[3];
    const void* a_dst = d_in[4];
    char* ws = (char*)d_ws;

    size_t off = 0;
    auto alloc = [&](size_t bytes) { size_t o = off; off += (bytes + 255) & ~(size_t)255; return o; };
    size_t flagsO  = alloc(64 * 4);
    size_t countsO = alloc((size_t)N_NODES * 4);
    size_t cursorO = alloc((size_t)N_NODES * 4);
    size_t zeroEnd = off;                       // [countsO, zeroEnd) gets memset 0
    size_t rowO    = alloc((size_t)(N_NODES + 1) * 4);
    size_t srcO    = alloc((size_t)N_EDGES * 4);
    size_t dstO    = alloc((size_t)N_EDGES * 4);
    size_t csrO    = alloc((size_t)N_EDGES * 4);
    size_t WfO     = alloc(16384 * 4);
    size_t afO     = alloc(256 * 4);
    size_t ssO     = alloc((size_t)N_NODES * 4 * 4);
    size_t sdO     = alloc((size_t)N_NODES * 4 * 4);
    size_t hO      = alloc((size_t)N_NODES * HF * 4);
    (void)ws_size; (void)in_sizes; (void)n_in;

    int*   flags   = (int*)(ws + flagsO);
    int*   counts  = (int*)(ws + countsO);
    int*   cursor  = (int*)(ws + cursorO);
    int*   rowSt   = (int*)(ws + rowO);
    int*   srcI    = (int*)(ws + srcO);
    int*   dstI    = (int*)(ws + dstO);
    int*   csr     = (int*)(ws + csrO);
    float* Wf      = (float*)(ws + WfO);
    float* af      = (float*)(ws + afO);
    float* s_src   = (float*)(ws + ssO);
    float* s_dst   = (float*)(ws + sdO);
    float* h       = (float*)(ws + hO);
    float* outF    = (float*)d_out;

    hipMemsetAsync(ws + countsO, 0, zeroEnd - countsO, stream);
    hipMemsetAsync(d_out, 0, (size_t)out_size * sizeof(float), stream);

    k_sniff<<<1, 64, 0, stream>>>(x, eidx, flags);
    k_convert<<<(N_EDGES + 255) / 256, 256, 0, stream>>>(W, a_src, a_dst, eidx, Wf, af, srcI, dstI, flags);
    k_gemm<<<(N_NODES + 31) / 32, 256, 0, stream>>>(x, Wf, af, h, s_src, s_dst, flags);
    k_count<<<(N_EDGES + 255) / 256, 256, 0, stream>>>(dstI, counts);
    k_scan<<<1, 1024, 0, stream>>>(counts, rowSt);
    k_scatter<<<(N_EDGES + 255) / 256, 256, 0, stream>>>(dstI, rowSt, cursor, csr);
    k_agg<<<(N_NODES + 3) / 4, 256, 0, stream>>>(h, s_src, s_dst, srcI, rowSt, csr, outF);
}

// Round 3
// 230.271 us; speedup vs baseline: 2.0142x; 2.0142x over previous
//
#include <hip/hip_runtime.h>
#include <stdint.h>

#define N_NODES 50000
#define N_EDGES 800000
#define HF 128          // HEADS * OUT_F
#define NEG_SLOPE 0.2f
#define EPS_F 1e-8f

typedef __attribute__((ext_vector_type(8))) short short8;
typedef __attribute__((ext_vector_type(4))) float f32x4;

// ---------- helpers ----------
__device__ __forceinline__ float bf2f(unsigned short u) {
    union { unsigned int i; float f; } v; v.i = ((unsigned int)u) << 16; return v.f;
}
__device__ __forceinline__ unsigned short f2bf(float f) {
    union { unsigned int i; float f; } v; v.f = f;
    unsigned int b = v.i;
    unsigned int r = (b + 0x7FFFu + ((b >> 16) & 1u)) >> 16;   // round-to-nearest-even
    return (unsigned short)r;
}
__device__ __forceinline__ float leaky(float v) { return v > 0.f ? v : NEG_SLOPE * v; }

// ---------- K0: dtype sniff ----------
__global__ void k_sniff(const void* x, const void* eidx, int* flags) {
    int l = threadIdx.x;  // 64 threads
    const unsigned short* xu = (const unsigned short*)x;
    float f = bf2f(xu[2 * l]);
    float af = fabsf(f);
    bool extreme = !(af <= 1e6f) || (f != 0.0f && af < 1e-7f);
    unsigned long long mask = __ballot(extreme);
    const unsigned int* eu = (const unsigned int*)eidx;
    unsigned int w = eu[2 * l + 1];
    unsigned long long mask2 = __ballot(w != 0u);
    if (l == 0) {
        flags[0] = (__popcll(mask) >= 8) ? 0 : 1;   // 1 = bf16 floats
        flags[1] = (__popcll(mask2) >= 4) ? 0 : 1;  // 1 = int64 indices
    }
}

// ---------- K1: normalize W->bf16, a_src/a_dst->f32, edges->int32, fused degree count ----------
__global__ void k_convert(const void* W, const void* a_src, const void* a_dst, const void* eidx,
                          unsigned short* Wbf, float* af, int* srcI, int* dstI, int* counts,
                          const int* flags) {
    int i = blockIdx.x * blockDim.x + threadIdx.x;
    int isB = flags[0], is64 = flags[1];
    if (i < 16384) Wbf[i] = isB ? ((const unsigned short*)W)[i] : f2bf(((const float*)W)[i]);
    if (i < 128) {
        af[i]       = isB ? bf2f(((const unsigned short*)a_src)[i]) : ((const float*)a_src)[i];
        af[128 + i] = isB ? bf2f(((const unsigned short*)a_dst)[i]) : ((const float*)a_dst)[i];
    }
    if (i < N_EDGES) {
        int s, d;
        if (is64) {
            s = (int)((const long long*)eidx)[i];
            d = (int)((const long long*)eidx)[N_EDGES + i];
        } else {
            s = ((const int*)eidx)[i];
            d = ((const int*)eidx)[N_EDGES + i];
        }
        srcI[i] = s; dstI[i] = d;
        atomicAdd(&counts[d], 1);
    }
}

// ---------- K2: MFMA GEMM  h = x @ W^T (bf16), fused scores s_src/s_dst ----------
// Block 256 = 4 waves; 64 nodes/block; each wave: 16 nodes x 128 outs.
__global__ __launch_bounds__(256) void k_gemm(const void* x, const unsigned short* Wbf, const float* af,
                                              unsigned short* h, float* s_src, float* s_dst,
                                              const int* flags) {
    __shared__ short xl[64 * 136];    // [row][k] bf16, padded 128->136
    __shared__ short wl[128 * 136];   // [o][k] bf16, padded
    int tid = threadIdx.x;
    int isB = flags[0];
    int nb = blockIdx.x * 64;
    const unsigned short* xu = (const unsigned short*)x;
    const float* xf = (const float*)x;

    // stage W [o][k]
    #pragma unroll
    for (int it = 0; it < 8; ++it) {
        int o = (tid >> 4) + it * 16;
        int k8 = (tid & 15) * 8;
        *(short8*)&wl[o * 136 + k8] = *(const short8*)&Wbf[o * 128 + k8];
    }
    // stage x tile (convert to bf16 if f32)
    #pragma unroll
    for (int it = 0; it < 4; ++it) {
        int row = (tid >> 4) + it * 16;
        int k8 = (tid & 15) * 8;
        int node = nb + row;
        short8 val;
        if (node < N_NODES) {
            if (isB) {
                val = *(const short8*)&xu[(size_t)node * 128 + k8];
            } else {
                float4 f0 = *(const float4*)&xf[(size_t)node * 128 + k8];
                float4 f1 = *(const float4*)&xf[(size_t)node * 128 + k8 + 4];
                val[0] = (short)f2bf(f0.x); val[1] = (short)f2bf(f0.y);
                val[2] = (short)f2bf(f0.z); val[3] = (short)f2bf(f0.w);
                val[4] = (short)f2bf(f1.x); val[5] = (short)f2bf(f1.y);
                val[6] = (short)f2bf(f1.z); val[7] = (short)f2bf(f1.w);
            }
        } else {
            val = short8{0,0,0,0,0,0,0,0};
        }
        *(short8*)&xl[row * 136 + k8] = val;
    }
    __syncthreads();

    int wv = tid >> 6, l = tid & 63;
    int lr = l & 15, lg = l >> 4;     // fragment row/col = lr, k-group = lg

    f32x4 acc0 = {0,0,0,0}, acc1 = {0,0,0,0}, acc2 = {0,0,0,0}, acc3 = {0,0,0,0};
    f32x4 acc4 = {0,0,0,0}, acc5 = {0,0,0,0}, acc6 = {0,0,0,0}, acc7 = {0,0,0,0};
    #pragma unroll
    for (int kb = 0; kb < 4; ++kb) {
        short8 a = *(const short8*)&xl[(wv * 16 + lr) * 136 + kb * 32 + lg * 8];
        short8 b0 = *(const short8*)&wl[(0 * 16 + lr) * 136 + kb * 32 + lg * 8];
        short8 b1 = *(const short8*)&wl[(1 * 16 + lr) * 136 + kb * 32 + lg * 8];
        short8 b2 = *(const short8*)&wl[(2 * 16 + lr) * 136 + kb * 32 + lg * 8];
        short8 b3 = *(const short8*)&wl[(3 * 16 + lr) * 136 + kb * 32 + lg * 8];
        short8 b4 = *(const short8*)&wl[(4 * 16 + lr) * 136 + kb * 32 + lg * 8];
        short8 b5 = *(const short8*)&wl[(5 * 16 + lr) * 136 + kb * 32 + lg * 8];
        short8 b6 = *(const short8*)&wl[(6 * 16 + lr) * 136 + kb * 32 + lg * 8];
        short8 b7 = *(const short8*)&wl[(7 * 16 + lr) * 136 + kb * 32 + lg * 8];
        acc0 = __builtin_amdgcn_mfma_f32_16x16x32_bf16(a, b0, acc0, 0, 0, 0);
        acc1 = __builtin_amdgcn_mfma_f32_16x16x32_bf16(a, b1, acc1, 0, 0, 0);
        acc2 = __builtin_amdgcn_mfma_f32_16x16x32_bf16(a, b2, acc2, 0, 0, 0);
        acc3 = __builtin_amdgcn_mfma_f32_16x16x32_bf16(a, b3, acc3, 0, 0, 0);
        acc4 = __builtin_amdgcn_mfma_f32_16x16x32_bf16(a, b4, acc4, 0, 0, 0);
        acc5 = __builtin_amdgcn_mfma_f32_16x16x32_bf16(a, b5, acc5, 0, 0, 0);
        acc6 = __builtin_amdgcn_mfma_f32_16x16x32_bf16(a, b6, acc6, 0, 0, 0);
        acc7 = __builtin_amdgcn_mfma_f32_16x16x32_bf16(a, b7, acc7, 0, 0, 0);
    }

    // epilogue: C/D layout col=lane&15, row=(lane>>4)*4+reg  [HW-verified]
    // node n_r = nb + wv*16 + lg*4 + r ; out o = ot*16 + lr ; head = ot>>1
    float pS[4][4], pD[4][4];
    #pragma unroll
    for (int r = 0; r < 4; ++r)
        #pragma unroll
        for (int hd = 0; hd < 4; ++hd) { pS[r][hd] = 0.f; pD[r][hd] = 0.f; }

    #define EPI(OT, ACC) { \
        float aSv = af[(OT) * 16 + lr]; \
        float aDv = af[128 + (OT) * 16 + lr]; \
        _Pragma("unroll") \
        for (int r = 0; r < 4; ++r) { \
            int n = nb + wv * 16 + lg * 4 + r; \
            float v = ACC[r]; \
            if (n < N_NODES) h[(size_t)n * HF + (OT) * 16 + lr] = f2bf(v); \
            pS[r][(OT) >> 1] += v * aSv; \
            pD[r][(OT) >> 1] += v * aDv; \
        } }
    EPI(0, acc0) EPI(1, acc1) EPI(2, acc2) EPI(3, acc3)
    EPI(4, acc4) EPI(5, acc5) EPI(6, acc6) EPI(7, acc7)
    #undef EPI

    // reduce over the 16 col-lanes (lane bits 0..3)
    #pragma unroll
    for (int off = 1; off < 16; off <<= 1) {
        #pragma unroll
        for (int r = 0; r < 4; ++r)
            #pragma unroll
            for (int hd = 0; hd < 4; ++hd) {
                pS[r][hd] += __shfl_xor(pS[r][hd], off, 64);
                pD[r][hd] += __shfl_xor(pD[r][hd], off, 64);
            }
    }
    if (lr == 0) {
        #pragma unroll
        for (int r = 0; r < 4; ++r) {
            int n = nb + wv * 16 + lg * 4 + r;
            if (n < N_NODES) {
                #pragma unroll
                for (int hd = 0; hd < 4; ++hd) {
                    s_src[n * 4 + hd] = pS[r][hd];
                    s_dst[n * 4 + hd] = pD[r][hd];
                }
            }
        }
    }
}

// ---------- K4a/b/c: coalesced 3-phase exclusive scan ----------
__global__ __launch_bounds__(1024) void k_scan1(const int* counts, int* row_start, int* btot) {
    __shared__ int buf[1024];
    int t = threadIdx.x;
    int i = blockIdx.x * 1024 + t;
    int c = (i < N_NODES) ? counts[i] : 0;
    buf[t] = c;
    __syncthreads();
    for (int off = 1; off < 1024; off <<= 1) {
        int v = (t >= off) ? buf[t - off] : 0;
        __syncthreads();
        buf[t] += v;
        __syncthreads();
    }
    if (i < N_NODES) row_start[i] = buf[t] - c;   // exclusive within block
    if (t == 1023) btot[blockIdx.x] = buf[1023];
}
__global__ void k_scan2(int* btot, int* row_start, int nblk) {
    int l = threadIdx.x;  // 64 threads
    int v = (l < nblk) ? btot[l] : 0;
    int inc = v;
    for (int off = 1; off < 64; off <<= 1) {
        int u = __shfl_up(inc, off, 64);
        if (l >= off) inc += u;
    }
    int tot = __shfl(inc, nblk - 1, 64);
    if (l < nblk) btot[l] = inc - v;              // exclusive block offsets
    if (l == 0) row_start[N_NODES] = tot;
}
__global__ __launch_bounds__(1024) void k_scan3(int* row_start, const int* btot) {
    int i = blockIdx.x * 1024 + threadIdx.x;
    if (i < N_NODES) row_start[i] += btot[blockIdx.x];
}

// ---------- K5: scatter SRC ids into CSR slots ----------
__global__ void k_scatter(const int* srcI, const int* dstI, const int* row_start, int* cursor,
                          int* csr_src) {
    int i = blockIdx.x * blockDim.x + threadIdx.x;
    if (i < N_EDGES) {
        int d = dstI[i];
        int p = atomicAdd(&cursor[d], 1);
        csr_src[row_start[d] + p] = srcI[i];
    }
}

// ---------- K6: per-node softmax + aggregation (1 wave = 1 node, bf16 h) ----------
__global__ __launch_bounds__(256) void k_agg(const unsigned short* h, const float* s_src,
                                             const float* s_dst, const int* row_start,
                                             const int* csr_src, float* out) {
    __shared__ float wts[4][64 * 4];
    __shared__ int   srcs[4][64];
    int wid = threadIdx.x >> 6;
    int l = threadIdx.x & 63;
    int n = blockIdx.x * 4 + wid;
    if (n >= N_NODES) return;
    int rs = row_start[n];
    int deg = row_start[n + 1] - rs;
    if (deg == 0) {
        *(float2*)&out[(size_t)n * HF + 2 * l] = make_float2(0.f, 0.f);
        return;
    }
    float4 sd = *(const float4*)&s_dst[n * 4];
    const float NI = -__builtin_inff();
    int hd4 = l >> 4;                     // head of output elems 2l, 2l+1
    float acc0 = 0.f, acc1 = 0.f;

    if (deg <= 64) {
        // ---- single chunk: scores live in registers ----
        int s = 0; float v0 = NI, v1 = NI, v2 = NI, v3 = NI;
        if (l < deg) {
            s = csr_src[rs + l];
            float4 ss = *(const float4*)&s_src[s * 4];
            v0 = leaky(ss.x + sd.x); v1 = leaky(ss.y + sd.y);
            v2 = leaky(ss.z + sd.z); v3 = leaky(ss.w + sd.w);
        }
        float m0 = v0, m1 = v1, m2 = v2, m3 = v3;
        #pragma unroll
        for (int off = 32; off >= 1; off >>= 1) {
            m0 = fmaxf(m0, __shfl_xor(m0, off, 64));
            m1 = fmaxf(m1, __shfl_xor(m1, off, 64));
            m2 = fmaxf(m2, __shfl_xor(m2, off, 64));
            m3 = fmaxf(m3, __shfl_xor(m3, off, 64));
        }
        float e0 = 0.f, e1 = 0.f, e2 = 0.f, e3 = 0.f;
        if (l < deg) {
            e0 = __expf(v0 - m0); e1 = __expf(v1 - m1);
            e2 = __expf(v2 - m2); e3 = __expf(v3 - m3);
        }
        float z0 = e0, z1 = e1, z2 = e2, z3 = e3;
        #pragma unroll
        for (int off = 32; off >= 1; off >>= 1) {
            z0 += __shfl_xor(z0, off, 64);
            z1 += __shfl_xor(z1, off, 64);
            z2 += __shfl_xor(z2, off, 64);
            z3 += __shfl_xor(z3, off, 64);
        }
        if (l < deg) {
            float4 w = make_float4(e0 / (z0 + EPS_F), e1 / (z1 + EPS_F),
                                   e2 / (z2 + EPS_F), e3 / (z3 + EPS_F));
            *(float4*)&wts[wid][l * 4] = w;
            srcs[wid][l] = s;
        }
        #pragma unroll 4
        for (int i = 0; i < deg; ++i) {
            int si = srcs[wid][i];
            float w = wts[wid][i * 4 + hd4];
            unsigned int u = *(const unsigned int*)&h[(size_t)si * HF + 2 * l];
            acc0 += w * bf2f((unsigned short)(u & 0xFFFFu));
            acc1 += w * bf2f((unsigned short)(u >> 16));
        }
    } else {
        // ---- multi chunk (rare) ----
        float m0 = NI, m1 = NI, m2 = NI, m3 = NI;
        for (int c = 0; c < deg; c += 64) {
            int e = c + l;
            if (e < deg) {
                int s = csr_src[rs + e];
                float4 ss = *(const float4*)&s_src[s * 4];
                m0 = fmaxf(m0, leaky(ss.x + sd.x)); m1 = fmaxf(m1, leaky(ss.y + sd.y));
                m2 = fmaxf(m2, leaky(ss.z + sd.z)); m3 = fmaxf(m3, leaky(ss.w + sd.w));
            }
        }
        #pragma unroll
        for (int off = 32; off >= 1; off >>= 1) {
            m0 = fmaxf(m0, __shfl_xor(m0, off, 64));
            m1 = fmaxf(m1, __shfl_xor(m1, off, 64));
            m2 = fmaxf(m2, __shfl_xor(m2, off, 64));
            m3 = fmaxf(m3, __shfl_xor(m3, off, 64));
        }
        float z0 = 0.f, z1 = 0.f, z2 = 0.f, z3 = 0.f;
        for (int c = 0; c < deg; c += 64) {
            int e = c + l;
            if (e < deg) {
                int s = csr_src[rs + e];
                float4 ss = *(const float4*)&s_src[s * 4];
                z0 += __expf(leaky(ss.x + sd.x) - m0);
                z1 += __expf(leaky(ss.y + sd.y) - m1);
                z2 += __expf(leaky(ss.z + sd.z) - m2);
                z3 += __expf(leaky(ss.w + sd.w) - m3);
            }
        }
        #pragma unroll
        for (int off = 32; off >= 1; off >>= 1) {
            z0 += __shfl_xor(z0, off, 64);
            z1 += __shfl_xor(z1, off, 64);
            z2 += __shfl_xor(z2, off, 64);
            z3 += __shfl_xor(z3, off, 64);
        }
        float i0 = 1.f / (z0 + EPS_F), i1 = 1.f / (z1 + EPS_F);
        float i2 = 1.f / (z2 + EPS_F), i3 = 1.f / (z3 + EPS_F);
        for (int c = 0; c < deg; c += 64) {
            int e = c + l;
            if (e < deg) {
                int s = csr_src[rs + e];
                float4 ss = *(const float4*)&s_src[s * 4];
                float4 w = make_float4(__expf(leaky(ss.x + sd.x) - m0) * i0,
                                       __expf(leaky(ss.y + sd.y) - m1) * i1,
                                       __expf(leaky(ss.z + sd.z) - m2) * i2,
                                       __expf(leaky(ss.w + sd.w) - m3) * i3);
                *(float4*)&wts[wid][l * 4] = w;
                srcs[wid][l] = s;
            }
            int lim = min(64, deg - c);
            #pragma unroll 4
            for (int i = 0; i < lim; ++i) {
                int si = srcs[wid][i];
                float w = wts[wid][i * 4 + hd4];
                unsigned int u = *(const unsigned int*)&h[(size_t)si * HF + 2 * l];
                acc0 += w * bf2f((unsigned short)(u & 0xFFFFu));
                acc1 += w * bf2f((unsigned short)(u >> 16));
            }
        }
    }
    *(float2*)&out[(size_t)n * HF + 2 * l] = make_float2(acc0, acc1);
}

extern "C" void kernel_launch(void* const* d_in, const int* in_sizes, int n_in,
                              void* d_out, int out_size, void* d_ws, size_t ws_size,
                              hipStream_t stream) {
    const void* x     = d_in[0];
    const void* eidx  = d_in[1];
    const void* W     = d_in[2];
    const void* a_src = d_in[3];
    const void* a_dst = d_in[4];
    char* ws = (char*)d_ws;

    size_t off = 0;
    auto alloc = [&](size_t bytes) { size_t o = off; off += (bytes + 255) & ~(size_t)255; return o; };
    size_t flagsO  = alloc(64 * 4);
    size_t countsO = alloc((size_t)N_NODES * 4);
    size_t cursorO = alloc((size_t)N_NODES * 4);
    size_t zeroEnd = off;                       // [countsO, zeroEnd) memset 0
    size_t rowO    = alloc((size_t)(N_NODES + 1) * 4);
    size_t btotO   = alloc(64 * 4);
    size_t srcO    = alloc((size_t)N_EDGES * 4);
    size_t dstO    = alloc((size_t)N_EDGES * 4);
    size_t csrO    = alloc((size_t)N_EDGES * 4);
    size_t WbO     = alloc(16384 * 2);
    size_t afO     = alloc(256 * 4);
    size_t ssO     = alloc((size_t)N_NODES * 4 * 4);
    size_t sdO     = alloc((size_t)N_NODES * 4 * 4);
    size_t hO      = alloc((size_t)N_NODES * HF * 2);
    (void)ws_size; (void)in_sizes; (void)n_in;

    int*   flags   = (int*)(ws + flagsO);
    int*   counts  = (int*)(ws + countsO);
    int*   cursor  = (int*)(ws + cursorO);
    int*   rowSt   = (int*)(ws + rowO);
    int*   btot    = (int*)(ws + btotO);
    int*   srcI    = (int*)(ws + srcO);
    int*   dstI    = (int*)(ws + dstO);
    int*   csrS    = (int*)(ws + csrO);
    unsigned short* Wbf = (unsigned short*)(ws + WbO);
    float* af      = (float*)(ws + afO);
    float* s_src   = (float*)(ws + ssO);
    float* s_dst   = (float*)(ws + sdO);
    unsigned short* h = (unsigned short*)(ws + hO);
    float* outF    = (float*)d_out;

    hipMemsetAsync(ws + countsO, 0, zeroEnd - countsO, stream);

    const int SCAN_BLKS = (N_NODES + 1023) / 1024;   // 49
    k_sniff<<<1, 64, 0, stream>>>(x, eidx, flags);
    k_convert<<<(N_EDGES + 255) / 256, 256, 0, stream>>>(W, a_src, a_dst, eidx, Wbf, af, srcI, dstI, counts, flags);
    k_gemm<<<(N_NODES + 63) / 64, 256, 0, stream>>>(x, Wbf, af, h, s_src, s_dst, flags);
    k_scan1<<<SCAN_BLKS, 1024, 0, stream>>>(counts, rowSt, btot);
    k_scan2<<<1, 64, 0, stream>>>(btot, rowSt, SCAN_BLKS);
    k_scan3<<<SCAN_BLKS, 1024, 0, stream>>>(rowSt, btot);
    k_scatter<<<(N_EDGES + 255) / 256, 256, 0, stream>>>(srcI, dstI, rowSt, cursor, csrS);
    k_agg<<<(N_NODES + 3) / 4, 256, 0, stream>>>(h, s_src, s_dst, rowSt, csrS, outF);
}